// Round 9
// baseline (235.894 us; speedup 1.0000x reference)
//
#include <hip/hip_runtime.h>
#include <hip/hip_bf16.h>
#include <stdint.h>

#define NH 16
#define DM 1024
#define DKV 64
#define BB 4
#define LL 2048
#define MT (BB*LL)   // 8192 rows total
#define NT (LL/64)   // 32 kv tiles

typedef __bf16 bf16;
typedef __bf16 bf16x8 __attribute__((ext_vector_type(8)));
typedef float f32x4 __attribute__((ext_vector_type(4)));
typedef float f32x16 __attribute__((ext_vector_type(16)));
typedef unsigned int u32x2 __attribute__((ext_vector_type(2)));
typedef unsigned int u32x4 __attribute__((ext_vector_type(4)));

template <int V> struct ic { static constexpr int v = V; };

__device__ __forceinline__ void gload_lds16(const void* g, void* l) {
  __builtin_amdgcn_global_load_lds(
      (const __attribute__((address_space(1))) unsigned int*)g,
      (__attribute__((address_space(3))) unsigned int*)l, 16, 0, 0);
}

__device__ __forceinline__ unsigned short bfbits(float x) {
  bf16 b = (bf16)x;
  return __builtin_bit_cast(unsigned short, b);
}

// single-instruction 2^x (v_exp_f32); exp2f() routes through ocml (round-3 regression)
__device__ __forceinline__ float fast_exp2(float x) {
#if defined(__has_builtin)
#if __has_builtin(__builtin_amdgcn_exp2f)
  return __builtin_amdgcn_exp2f(x);
#else
  float r; asm("v_exp_f32 %0, %1" : "=v"(r) : "v"(x)); return r;
#endif
#else
  float r; asm("v_exp_f32 %0, %1" : "=v"(r) : "v"(x)); return r;
#endif
}

#if defined(__has_builtin)
#if __has_builtin(__builtin_amdgcn_permlane32_swap)
#define HAVE_PLSWAP 1
#endif
#endif

// swap: r.x = (lane<32)? a : b[partner];  r.y = (lane<32)? a[partner] : b
__device__ __forceinline__ u32x2 plswap(unsigned int a, unsigned int b, int hi) {
#ifdef HAVE_PLSWAP
  auto rr = __builtin_amdgcn_permlane32_swap(a, b, false, false);
  u32x2 r; r.x = rr[0]; r.y = rr[1];
  return r;
#else
  unsigned int pa = (unsigned int)__shfl_xor((int)a, 32);
  unsigned int pb_ = (unsigned int)__shfl_xor((int)b, 32);
  u32x2 r;
  r.x = hi ? pb_ : a;
  r.y = hi ? b : pa;
  return r;
#endif
}

// ---------------- cast f32 -> bf16, 8 elems/thread; grid.y selects buffer ------------
__global__ __launch_bounds__(256) void cast3_f32_to_bf16(const float* __restrict__ i0,
                                                         const float* __restrict__ i1,
                                                         const float* __restrict__ i2,
                                                         bf16* __restrict__ o0,
                                                         bf16* __restrict__ o1,
                                                         bf16* __restrict__ o2, int n8) {
  const float* in = blockIdx.y == 0 ? i0 : (blockIdx.y == 1 ? i1 : i2);
  bf16* out = blockIdx.y == 0 ? o0 : (blockIdx.y == 1 ? o1 : o2);
  int i = blockIdx.x * blockDim.x + threadIdx.x;
  if (i >= n8) return;
  const float4* p = (const float4*)in + (size_t)i * 2;
  float4 a = p[0], b = p[1];
  bf16x8 r;
  r[0] = (bf16)a.x; r[1] = (bf16)a.y; r[2] = (bf16)a.z; r[3] = (bf16)a.w;
  r[4] = (bf16)b.x; r[5] = (bf16)b.y; r[6] = (bf16)b.z; r[7] = (bf16)b.w;
  *((bf16x8*)out + i) = r;
}

__global__ __launch_bounds__(256) void cast_f32_to_bf16(const float* __restrict__ in,
                                                        bf16* __restrict__ out, int n8) {
  int i = blockIdx.x * blockDim.x + threadIdx.x;
  if (i >= n8) return;
  const float4* p = (const float4*)in + (size_t)i * 2;
  float4 a = p[0], b = p[1];
  bf16x8 r;
  r[0] = (bf16)a.x; r[1] = (bf16)a.y; r[2] = (bf16)a.z; r[3] = (bf16)a.w;
  r[4] = (bf16)b.x; r[5] = (bf16)b.y; r[6] = (bf16)b.z; r[7] = (bf16)b.w;
  *((bf16x8*)out + i) = r;
}

// ---------------- repack w[h][d][kk] (f32) -> wt[h*64+kk][d] (bf16) ----------------
__global__ __launch_bounds__(256) void repack_w(const float* __restrict__ w0, const float* __restrict__ w1,
                                                const float* __restrict__ w2,
                                                bf16* __restrict__ o0, bf16* __restrict__ o1,
                                                bf16* __restrict__ o2) {
  const float* w = blockIdx.z == 0 ? w0 : (blockIdx.z == 1 ? w1 : w2);
  bf16* o = blockIdx.z == 0 ? o0 : (blockIdx.z == 1 ? o1 : o2);
  __shared__ float t[64][65];
  int h = blockIdx.y, d0 = blockIdx.x * 64;
  const float* src = w + ((size_t)h * DM + d0) * DKV;
  for (int i = threadIdx.x; i < 64 * 64; i += 256) {
    int r = i >> 6, c = i & 63;
    t[r][c] = src[(size_t)r * DKV + c];
  }
  __syncthreads();
  for (int i = threadIdx.x; i < 64 * 64; i += 256) {
    int kk = i >> 6, d = i & 63;
    o[((size_t)(h * 64 + kk)) * DM + d0 + d] = (bf16)t[d][kk];
  }
}

// ---------------- QKV projection GEMMs: 256x256 tile, 8 waves, 8-phase schedule ------
// blockIdx.z: 0 -> QH (scale (1/32)*log2e), 1 -> KH, 2 -> VT (transposed out).
// BM=BN=256, BK=64, 2-buffer LDS (128 KB), counted vmcnt gates (T3+T4), T5 setprio.
__global__ __launch_bounds__(512, 2) void gemm_qkv256(const bf16* __restrict__ Xq, const bf16* __restrict__ Xk,
                                                      const bf16* __restrict__ Xv, const bf16* __restrict__ Wqt,
                                                      const bf16* __restrict__ Wkt, const bf16* __restrict__ Wvt,
                                                      bf16* __restrict__ QH, bf16* __restrict__ KH,
                                                      bf16* __restrict__ VT) {
  __shared__ bf16 sA[2][256 * 64];
  __shared__ bf16 sB[2][256 * 64];
  const int mode = blockIdx.z;
  const bf16* Ap  = mode == 0 ? Xq : (mode == 1 ? Xk : Xv);
  const bf16* Btp = mode == 0 ? Wqt : (mode == 1 ? Wkt : Wvt);
  const int tid = threadIdx.x;
  const int wid = tid >> 6, l = tid & 63;
  const int cc = l & 15, g4 = l >> 4;
  const int wr = wid >> 2, wc = wid & 3;            // 2 x 4 wave grid
  const int m0 = blockIdx.y * 256, n0 = blockIdx.x * 256;

  f32x4 acc[8][4] = {};

  // stage one half-tile (128 rows x 64 cols) of A or B for K-tile `stile` (clamped)
  auto STAGEH = [&](auto SB_, auto SI_, auto SH_, int stile) {
    constexpr int SBUF = decltype(SB_)::v, SISB = decltype(SI_)::v, SHALF = decltype(SH_)::v;
    int kk = (stile < 16 ? stile : 15) * 64;
    const bf16* sp = SISB ? Btp : Ap;
    int b0 = SISB ? n0 : m0;
    char* db = (char*)(SISB ? &sB[SBUF][0] : &sA[SBUF][0]);
#pragma unroll
    for (int j = 0; j < 2; ++j) {
      int gb = (j * 8 + wid) * 64;                  // granule base (wave-uniform)
      int g = gb + l;                               // lane granule 0..1023
      int rl = g >> 3, gl = g & 7;
      int row = SHALF * 128 + rl;
      int slot = gl ^ (row & 7);                    // inverse-swizzled source granule
      gload_lds16(sp + (size_t)(b0 + row) * 1024 + kk + slot * 8,
                  db + (SHALF * 1024 + gb) * 16);
    }
  };

  // one phase: 12 ds_reads (quadrant MH x NHF of buffer BUF), stage one half-tile,
  // barrier, lgkmcnt(0), 16 MFMA, optional vmcnt gate, barrier.
  auto PHASE = [&](auto MH_, auto NH_, auto BUF_, auto SB_, auto SI_, auto SH_,
                   int stile, auto GATE_) {
    constexpr int MH = decltype(MH_)::v, NHF = decltype(NH_)::v, BUF = decltype(BUF_)::v;
    constexpr int GATE = decltype(GATE_)::v;
    bf16x8 af[4][2], bfv[2][2];
#pragma unroll
    for (int x2 = 0; x2 < 4; ++x2) {
      int ar = (2 * (MH * 4 + x2) + wr) * 16 + cc;
#pragma unroll
      for (int ks = 0; ks < 2; ++ks)
        af[x2][ks] = *(const bf16x8*)((const char*)&sA[BUF][0] + ar * 128 +
                                      (((ks * 4 + g4) ^ (ar & 7)) * 16));
    }
#pragma unroll
    for (int y2 = 0; y2 < 2; ++y2) {
      int br = (4 * (NHF * 2 + y2) + wc) * 16 + cc;
#pragma unroll
      for (int ks = 0; ks < 2; ++ks)
        bfv[y2][ks] = *(const bf16x8*)((const char*)&sB[BUF][0] + br * 128 +
                                       (((ks * 4 + g4) ^ (br & 7)) * 16));
    }
    STAGEH(SB_, SI_, SH_, stile);
    __builtin_amdgcn_s_barrier();
    asm volatile("s_waitcnt lgkmcnt(0)" ::: "memory");
    __builtin_amdgcn_sched_barrier(0);
    __builtin_amdgcn_s_setprio(1);
#pragma unroll
    for (int x2 = 0; x2 < 4; ++x2)
#pragma unroll
      for (int y2 = 0; y2 < 2; ++y2)
#pragma unroll
        for (int ks = 0; ks < 2; ++ks)
          acc[MH * 4 + x2][NHF * 2 + y2] = __builtin_amdgcn_mfma_f32_16x16x32_bf16(
              af[x2][ks], bfv[y2][ks], acc[MH * 4 + x2][NHF * 2 + y2], 0, 0, 0);
    __builtin_amdgcn_s_setprio(0);
    if constexpr (GATE == 8) asm volatile("s_waitcnt vmcnt(8)" ::: "memory");
    else if constexpr (GATE == 6) asm volatile("s_waitcnt vmcnt(6)" ::: "memory");
    else if constexpr (GATE == 4) asm volatile("s_waitcnt vmcnt(4)" ::: "memory");
    __builtin_amdgcn_s_barrier();
  };

  // prologue: K-tiles 0 -> buf0, 1 -> buf1 (full), drain, barrier
  STAGEH(ic<0>{}, ic<0>{}, ic<0>{}, 0); STAGEH(ic<0>{}, ic<0>{}, ic<1>{}, 0);
  STAGEH(ic<0>{}, ic<1>{}, ic<0>{}, 0); STAGEH(ic<0>{}, ic<1>{}, ic<1>{}, 0);
  STAGEH(ic<1>{}, ic<0>{}, ic<0>{}, 1); STAGEH(ic<1>{}, ic<0>{}, ic<1>{}, 1);
  STAGEH(ic<1>{}, ic<1>{}, ic<0>{}, 1); STAGEH(ic<1>{}, ic<1>{}, ic<1>{}, 1);
  asm volatile("s_waitcnt vmcnt(0)" ::: "memory");
  __builtin_amdgcn_s_barrier();

  // 8 iterations x 2 K-tiles (K=1024 / 64 = 16 tiles); stage targets derived so every
  // overwrite follows the overwritten region's last read by >= 1 barrier, and gates
  // vmcnt(8)@p3 / vmcnt(6)@p4 / vmcnt(4)@p7 drain exactly the loads read next.
  for (int i = 0; i < 8; ++i) {
    int t0 = 2 * i;
    PHASE(ic<0>{}, ic<0>{}, ic<0>{},  ic<1>{}, ic<0>{}, ic<1>{}, t0 + 1, ic<-1>{});  // p0
    PHASE(ic<0>{}, ic<1>{}, ic<0>{},  ic<1>{}, ic<1>{}, ic<1>{}, t0 + 1, ic<-1>{});  // p1
    PHASE(ic<1>{}, ic<0>{}, ic<0>{},  ic<0>{}, ic<0>{}, ic<0>{}, t0 + 2, ic<-1>{});  // p2
    PHASE(ic<1>{}, ic<1>{}, ic<0>{},  ic<0>{}, ic<1>{}, ic<0>{}, t0 + 2, ic<8>{});   // p3
    PHASE(ic<0>{}, ic<0>{}, ic<1>{},  ic<0>{}, ic<0>{}, ic<1>{}, t0 + 2, ic<6>{});   // p4
    PHASE(ic<0>{}, ic<1>{}, ic<1>{},  ic<0>{}, ic<1>{}, ic<1>{}, t0 + 2, ic<-1>{});  // p5
    PHASE(ic<1>{}, ic<0>{}, ic<1>{},  ic<1>{}, ic<0>{}, ic<0>{}, t0 + 3, ic<-1>{});  // p6
    PHASE(ic<1>{}, ic<1>{}, ic<1>{},  ic<1>{}, ic<1>{}, ic<0>{}, t0 + 3, ic<4>{});   // p7
  }

  // ---- epilogue ----
  if (mode < 2) {
    bf16* O = mode == 0 ? QH : KH;
    const float s = (mode == 0) ? 0.03125f * 1.44269504088896f : 1.0f;
#pragma unroll
    for (int x = 0; x < 8; ++x)
#pragma unroll
      for (int y = 0; y < 4; ++y)
#pragma unroll
        for (int r = 0; r < 4; ++r) {
          int m = m0 + (2 * x + wr) * 16 + g4 * 4 + r;
          int n = n0 + (4 * y + wc) * 16 + cc;
          O[(size_t)m * 1024 + n] = (bf16)(acc[x][y][r] * s);
        }
  } else {
    bf16* O = VT;  // Vt[(h*4+b)*64+dv][s]
#pragma unroll
    for (int x = 0; x < 8; ++x)
#pragma unroll
      for (int y = 0; y < 4; ++y) {
        int mb = m0 + (2 * x + wr) * 16 + g4 * 4;
        int n = n0 + (4 * y + wc) * 16 + cc;
        int bb2 = mb >> 11, sidx = mb & 2047;
        int hh2 = n >> 6, dv = n & 63;
        unsigned int u0 = bfbits(acc[x][y][0]) | ((unsigned int)bfbits(acc[x][y][1]) << 16);
        unsigned int u1 = bfbits(acc[x][y][2]) | ((unsigned int)bfbits(acc[x][y][3]) << 16);
        *(uint2*)(O + ((size_t)((hh2 * 4 + bb2) * 64 + dv)) * LL + sidx) = make_uint2(u0, u1);
      }
  }
}

// ---------------- final projection GEMM (128^2, proven) ----------------
__global__ __launch_bounds__(256) void gemm_proj(const bf16* __restrict__ A, const bf16* __restrict__ Bt,
                                                 float* __restrict__ Out, const float* __restrict__ bias) {
  __shared__ bf16 sA[128 * 64];
  __shared__ bf16 sB[128 * 64];
  const int tid = threadIdx.x;
  const int w = tid >> 6, l = tid & 63;
  const int c = l & 15, g4 = l >> 4;
  const int wm = w >> 1, wn = w & 1;
  const int m0 = blockIdx.y * 128, n0 = blockIdx.x * 128;

  f32x4 acc[4][4] = {};
  for (int kt = 0; kt < 1024; kt += 64) {
#pragma unroll
    for (int i = 0; i < 4; ++i) {
      int blk = i * 4 + w;
      int row = blk * 8 + (l >> 3);
      int g = (l & 7) ^ (row & 7);
      gload_lds16(A + ((size_t)(m0 + row)) * 1024 + kt + g * 8, (char*)sA + blk * 1024);
      gload_lds16(Bt + ((size_t)(n0 + row)) * 1024 + kt + g * 8, (char*)sB + blk * 1024);
    }
    __syncthreads();
#pragma unroll
    for (int ks = 0; ks < 2; ++ks) {
      bf16x8 af[4], bfr[4];
#pragma unroll
      for (int x = 0; x < 4; ++x) {
        int ar = wm * 64 + x * 16 + c;
        af[x] = *(const bf16x8*)((const char*)sA + ar * 128 + (((ks * 4 + g4) ^ (ar & 7)) * 16));
        int br = wn * 64 + x * 16 + c;
        bfr[x] = *(const bf16x8*)((const char*)sB + br * 128 + (((ks * 4 + g4) ^ (br & 7)) * 16));
      }
#pragma unroll
      for (int x = 0; x < 4; ++x)
#pragma unroll
        for (int y = 0; y < 4; ++y)
          acc[x][y] = __builtin_amdgcn_mfma_f32_16x16x32_bf16(af[x], bfr[y], acc[x][y], 0, 0, 0);
    }
    __syncthreads();
  }

  const int mm = m0 + wm * 64, nn = n0 + wn * 64;
#pragma unroll
  for (int x = 0; x < 4; ++x)
#pragma unroll
    for (int y = 0; y < 4; ++y)
#pragma unroll
      for (int r = 0; r < 4; ++r) {
        int m = mm + x * 16 + g4 * 4 + r;
        int n = nn + y * 16 + c;
        Out[(size_t)m * 1024 + n] = acc[x][y][r] + bias[n];
      }
}

// ---------------- flash attention: no-max softmax, ones-MFMA sums (round-8, proven) --
__global__ __launch_bounds__(256, 2) void attn_kernel(const bf16* __restrict__ qh,
                                                      const bf16* __restrict__ kh,
                                                      const bf16* __restrict__ vt,
                                                      bf16* __restrict__ o) {
  __shared__ bf16 sK[4][64 * 64];
  __shared__ bf16 sV[4][64 * 64];
  const int tid = threadIdx.x, w = tid >> 6, l = tid & 63;
  const int c = l & 31, hi = l >> 5;
  const int bh = blockIdx.x, b = bh & 3, h = bh >> 2;
  const int q0 = blockIdx.y * 256 + w * 64;

  const bf16* qbase = qh + ((size_t)(b * LL)) * DM + h * 64;
  const bf16* kbase = kh + ((size_t)(b * LL)) * DM + h * 64;
  const bf16* vbase = vt + ((size_t)((h * 4 + b) * 64)) * LL;

  bf16x8 qfA[4], qfB[4];
#pragma unroll
  for (int ks = 0; ks < 4; ++ks) {
    qfA[ks] = *(const bf16x8*)(qbase + (size_t)(q0 + c) * DM + ks * 16 + hi * 8);
    qfB[ks] = *(const bf16x8*)(qbase + (size_t)(q0 + 32 + c) * DM + ks * 16 + hi * 8);
  }

  bf16x8 onesf;
#pragma unroll
  for (int i = 0; i < 8; ++i) onesf[i] = (bf16)1.0f;

  f32x16 oA0 = {}, oA1 = {}, oB0 = {}, oB1 = {};
  f32x16 lAa = {}, lBa = {};

  auto STAGE = [&](int bufi, int kv0) {
#pragma unroll
    for (int j = 0; j < 2; ++j) {
      int gi = w * 128 + j * 64 + l;
      int row = gi >> 3;
      int g = (gi & 7) ^ (row & 7);
      gload_lds16(kbase + (size_t)(kv0 + row) * DM + g * 8,
                  (char*)sK[bufi] + (w * 128 + j * 64) * 16);
      gload_lds16(vbase + (size_t)row * LL + kv0 + g * 8,
                  (char*)sV[bufi] + (w * 128 + j * 64) * 16);
    }
  };

  auto EXPPACK = [&](f32x16& st0, f32x16& st1, bf16x8* pb) {
#pragma unroll
    for (int r = 0; r < 16; ++r) st0[r] = fast_exp2(st0[r]);
#pragma unroll
    for (int r = 0; r < 16; ++r) st1[r] = fast_exp2(st1[r]);
#pragma unroll
    for (int t = 0; t < 2; ++t) {
      const f32x16& st = t ? st1 : st0;
      unsigned int u[4][2];
#pragma unroll
      for (int g2 = 0; g2 < 4; ++g2) {
        u[g2][0] = (unsigned int)bfbits(st[4 * g2 + 0]) | ((unsigned int)bfbits(st[4 * g2 + 1]) << 16);
        u[g2][1] = (unsigned int)bfbits(st[4 * g2 + 2]) | ((unsigned int)bfbits(st[4 * g2 + 3]) << 16);
      }
      u32x2 s0 = plswap(u[0][0], u[1][0], hi);
      u32x2 s1 = plswap(u[0][1], u[1][1], hi);
      u32x4 w0; w0.x = s0.x; w0.y = s1.x; w0.z = s0.y; w0.w = s1.y;
      pb[2 * t] = __builtin_bit_cast(bf16x8, w0);
      u32x2 s2 = plswap(u[2][0], u[3][0], hi);
      u32x2 s3 = plswap(u[2][1], u[3][1], hi);
      u32x4 w1; w1.x = s2.x; w1.y = s3.x; w1.z = s2.y; w1.w = s3.y;
      pb[2 * t + 1] = __builtin_bit_cast(bf16x8, w1);
    }
  };

  auto TILE = [&](int bufi) {
    const char* Kb = (const char*)sK[bufi];
    const char* Vb = (const char*)sV[bufi];

    bf16x8 kf[8];
#pragma unroll
    for (int ks = 0; ks < 4; ++ks) {
      int slot = ((ks * 2 + hi) ^ (c & 7)) * 16;
      kf[ks]     = *(const bf16x8*)(Kb + c * 128 + slot);
      kf[4 + ks] = *(const bf16x8*)(Kb + (32 + c) * 128 + slot);
    }
    f32x16 sA0 = {}, sA1 = {}, sB0 = {}, sB1 = {};
    __builtin_amdgcn_s_setprio(1);
#pragma unroll
    for (int ks = 0; ks < 4; ++ks) {
      sA0 = __builtin_amdgcn_mfma_f32_32x32x16_bf16(kf[ks],     qfA[ks], sA0, 0, 0, 0);
      sA1 = __builtin_amdgcn_mfma_f32_32x32x16_bf16(kf[4 + ks], qfA[ks], sA1, 0, 0, 0);
    }
#pragma unroll
    for (int ks = 0; ks < 4; ++ks) {
      sB0 = __builtin_amdgcn_mfma_f32_32x32x16_bf16(kf[ks],     qfB[ks], sB0, 0, 0, 0);
      sB1 = __builtin_amdgcn_mfma_f32_32x32x16_bf16(kf[4 + ks], qfB[ks], sB1, 0, 0, 0);
    }
    __builtin_amdgcn_s_setprio(0);

    bf16x8 pbA[4];
    EXPPACK(sA0, sA1, pbA);

    bf16x8 vf[8];
#pragma unroll
    for (int ks = 0; ks < 4; ++ks) {
      int slot = ((ks * 2 + hi) ^ (c & 7)) * 16;
      vf[ks]     = *(const bf16x8*)(Vb + c * 128 + slot);
      vf[4 + ks] = *(const bf16x8*)(Vb + (32 + c) * 128 + slot);
    }
    __builtin_amdgcn_s_setprio(1);
#pragma unroll
    for (int ks = 0; ks < 4; ++ks) {
      oA0 = __builtin_amdgcn_mfma_f32_32x32x16_bf16(vf[ks],     pbA[ks], oA0, 0, 0, 0);
      oA1 = __builtin_amdgcn_mfma_f32_32x32x16_bf16(vf[4 + ks], pbA[ks], oA1, 0, 0, 0);
      lAa = __builtin_amdgcn_mfma_f32_32x32x16_bf16(onesf,      pbA[ks], lAa, 0, 0, 0);
    }
    __builtin_amdgcn_s_setprio(0);

    bf16x8 pbB[4];
    EXPPACK(sB0, sB1, pbB);
    __builtin_amdgcn_s_setprio(1);
#pragma unroll
    for (int ks = 0; ks < 4; ++ks) {
      oB0 = __builtin_amdgcn_mfma_f32_32x32x16_bf16(vf[ks],     pbB[ks], oB0, 0, 0, 0);
      oB1 = __builtin_amdgcn_mfma_f32_32x32x16_bf16(vf[4 + ks], pbB[ks], oB1, 0, 0, 0);
      lBa = __builtin_amdgcn_mfma_f32_32x32x16_bf16(onesf,      pbB[ks], lBa, 0, 0, 0);
    }
    __builtin_amdgcn_s_setprio(0);
  };

  STAGE(0, 0);
  STAGE(1, 64);

  for (int wd = 0; wd < 16; ++wd) {
    __builtin_amdgcn_s_barrier();
    int t2 = 2 * wd + 2;
    if (t2 < NT) {
      STAGE(t2 & 3, t2 * 64);
      STAGE((t2 + 1) & 3, (t2 + 1) * 64);
      asm volatile("s_waitcnt vmcnt(8)" ::: "memory");
    } else {
      asm volatile("s_waitcnt vmcnt(0)" ::: "memory");
    }
    TILE((2 * wd) & 3);
    TILE((2 * wd + 1) & 3);
  }

  bf16* ob = o + ((size_t)(b * LL)) * DM + h * 64;
  {
    float inv = 1.0f / lAa[0];
#pragma unroll
    for (int dt = 0; dt < 2; ++dt) {
      const f32x16& oc = dt ? oA1 : oA0;
#pragma unroll
      for (int rg = 0; rg < 4; ++rg) {
        int dv0 = dt * 32 + rg * 8 + hi * 4;
        unsigned int u0 = (unsigned int)bfbits(oc[rg * 4 + 0] * inv) |
                          ((unsigned int)bfbits(oc[rg * 4 + 1] * inv) << 16);
        unsigned int u1 = (unsigned int)bfbits(oc[rg * 4 + 2] * inv) |
                          ((unsigned int)bfbits(oc[rg * 4 + 3] * inv) << 16);
        *(uint2*)(ob + (size_t)(q0 + c) * DM + dv0) = make_uint2(u0, u1);
      }
    }
  }
  {
    float inv = 1.0f / lBa[0];
#pragma unroll
    for (int dt = 0; dt < 2; ++dt) {
      const f32x16& oc = dt ? oB1 : oB0;
#pragma unroll
      for (int rg = 0; rg < 4; ++rg) {
        int dv0 = dt * 32 + rg * 8 + hi * 4;
        unsigned int u0 = (unsigned int)bfbits(oc[rg * 4 + 0] * inv) |
                          ((unsigned int)bfbits(oc[rg * 4 + 1] * inv) << 16);
        unsigned int u1 = (unsigned int)bfbits(oc[rg * 4 + 2] * inv) |
                          ((unsigned int)bfbits(oc[rg * 4 + 3] * inv) << 16);
        *(uint2*)(ob + (size_t)(q0 + 32 + c) * DM + dv0) = make_uint2(u0, u1);
      }
    }
  }
}

extern "C" void kernel_launch(void* const* d_in, const int* in_sizes, int n_in,
                              void* d_out, int out_size, void* d_ws, size_t ws_size,
                              hipStream_t stream) {
  const float* q  = (const float*)d_in[0];
  const float* k  = (const float*)d_in[1];
  const float* v  = (const float*)d_in[2];
  const float* wq = (const float*)d_in[3];
  const float* wk = (const float*)d_in[4];
  const float* wv = (const float*)d_in[5];
  const float* pw = (const float*)d_in[6];
  const float* pb = (const float*)d_in[7];
  float* out = (float*)d_out;

  char* ws = (char*)d_ws;
  const size_t SX = (size_t)MT * DM * 2;   // 16.8 MB
  const size_t SW = (size_t)DM * DM * 2;   // 2 MB
  bf16* Xq  = (bf16*)(ws);
  bf16* Xk  = (bf16*)(ws + SX);
  bf16* Xv  = (bf16*)(ws + 2 * SX);
  bf16* Wqt = (bf16*)(ws + 3 * SX);
  bf16* Wkt = (bf16*)(ws + 3 * SX + SW);
  bf16* Wvt = (bf16*)(ws + 3 * SX + 2 * SW);
  bf16* Wp  = (bf16*)(ws + 3 * SX + 3 * SW);
  bf16* QH  = (bf16*)(ws + 3 * SX + 4 * SW);
  bf16* KH  = (bf16*)(ws + 4 * SX + 4 * SW);
  bf16* VT  = (bf16*)(ws + 5 * SX + 4 * SW);
  bf16* OO  = Xq;  // reuse: Xq dead after gemm_qkv256

  const int nx8 = MT * DM / 8;
  cast3_f32_to_bf16<<<dim3(nx8 / 256, 3), 256, 0, stream>>>(q, k, v, Xq, Xk, Xv, nx8);
  const int nw8 = DM * DM / 8;
  cast_f32_to_bf16<<<dim3(nw8 / 256), 256, 0, stream>>>(pw, Wp, nw8);
  repack_w<<<dim3(16, 16, 3), 256, 0, stream>>>(wq, wk, wv, Wqt, Wkt, Wvt);

  gemm_qkv256<<<dim3(4, 32, 3), 512, 0, stream>>>(Xq, Xk, Xv, Wqt, Wkt, Wvt, QH, KH, VT);

  attn_kernel<<<dim3(64, 8), 256, 0, stream>>>(QH, KH, VT, OO);

  gemm_proj<<<dim3(8, 64), 256, 0, stream>>>(OO, Wp, out, pb);
}

// Round 10
// 230.555 us; speedup vs baseline: 1.0232x; 1.0232x over previous
//
#include <hip/hip_runtime.h>
#include <hip/hip_bf16.h>
#include <stdint.h>

#define NH 16
#define DM 1024
#define DKV 64
#define BB 4
#define LL 2048
#define MT (BB*LL)   // 8192 rows total
#define NT (LL/64)   // 32 kv tiles

typedef __bf16 bf16;
typedef __bf16 bf16x8 __attribute__((ext_vector_type(8)));
typedef float f32x4 __attribute__((ext_vector_type(4)));
typedef float f32x16 __attribute__((ext_vector_type(16)));
typedef unsigned int u32x2 __attribute__((ext_vector_type(2)));
typedef unsigned int u32x4 __attribute__((ext_vector_type(4)));

__device__ __forceinline__ void gload_lds16(const void* g, void* l) {
  __builtin_amdgcn_global_load_lds(
      (const __attribute__((address_space(1))) unsigned int*)g,
      (__attribute__((address_space(3))) unsigned int*)l, 16, 0, 0);
}

__device__ __forceinline__ unsigned short bfbits(float x) {
  bf16 b = (bf16)x;
  return __builtin_bit_cast(unsigned short, b);
}

// single-instruction 2^x (v_exp_f32); exp2f() routes through ocml (round-3 regression)
__device__ __forceinline__ float fast_exp2(float x) {
#if defined(__has_builtin)
#if __has_builtin(__builtin_amdgcn_exp2f)
  return __builtin_amdgcn_exp2f(x);
#else
  float r; asm("v_exp_f32 %0, %1" : "=v"(r) : "v"(x)); return r;
#endif
#else
  float r; asm("v_exp_f32 %0, %1" : "=v"(r) : "v"(x)); return r;
#endif
}

#if defined(__has_builtin)
#if __has_builtin(__builtin_amdgcn_permlane32_swap)
#define HAVE_PLSWAP 1
#endif
#endif

// swap: r.x = (lane<32)? a : b[partner];  r.y = (lane<32)? a[partner] : b
__device__ __forceinline__ u32x2 plswap(unsigned int a, unsigned int b, int hi) {
#ifdef HAVE_PLSWAP
  auto rr = __builtin_amdgcn_permlane32_swap(a, b, false, false);
  u32x2 r; r.x = rr[0]; r.y = rr[1];
  return r;
#else
  unsigned int pa = (unsigned int)__shfl_xor((int)a, 32);
  unsigned int pb_ = (unsigned int)__shfl_xor((int)b, 32);
  u32x2 r;
  r.x = hi ? pb_ : a;
  r.y = hi ? b : pa;
  return r;
#endif
}

// ---------------- cast f32 -> bf16, 8 elems/thread; grid.y selects buffer ------------
__global__ __launch_bounds__(256) void cast3_f32_to_bf16(const float* __restrict__ i0,
                                                         const float* __restrict__ i1,
                                                         const float* __restrict__ i2,
                                                         bf16* __restrict__ o0,
                                                         bf16* __restrict__ o1,
                                                         bf16* __restrict__ o2, int n8) {
  const float* in = blockIdx.y == 0 ? i0 : (blockIdx.y == 1 ? i1 : i2);
  bf16* out = blockIdx.y == 0 ? o0 : (blockIdx.y == 1 ? o1 : o2);
  int i = blockIdx.x * blockDim.x + threadIdx.x;
  if (i >= n8) return;
  const float4* p = (const float4*)in + (size_t)i * 2;
  float4 a = p[0], b = p[1];
  bf16x8 r;
  r[0] = (bf16)a.x; r[1] = (bf16)a.y; r[2] = (bf16)a.z; r[3] = (bf16)a.w;
  r[4] = (bf16)b.x; r[5] = (bf16)b.y; r[6] = (bf16)b.z; r[7] = (bf16)b.w;
  *((bf16x8*)out + i) = r;
}

__global__ __launch_bounds__(256) void cast_f32_to_bf16(const float* __restrict__ in,
                                                        bf16* __restrict__ out, int n8) {
  int i = blockIdx.x * blockDim.x + threadIdx.x;
  if (i >= n8) return;
  const float4* p = (const float4*)in + (size_t)i * 2;
  float4 a = p[0], b = p[1];
  bf16x8 r;
  r[0] = (bf16)a.x; r[1] = (bf16)a.y; r[2] = (bf16)a.z; r[3] = (bf16)a.w;
  r[4] = (bf16)b.x; r[5] = (bf16)b.y; r[6] = (bf16)b.z; r[7] = (bf16)b.w;
  *((bf16x8*)out + i) = r;
}

// ---------------- repack w[h][d][kk] (f32) -> wt[h*64+kk][d] (bf16) ----------------
__global__ __launch_bounds__(256) void repack_w(const float* __restrict__ w0, const float* __restrict__ w1,
                                                const float* __restrict__ w2,
                                                bf16* __restrict__ o0, bf16* __restrict__ o1,
                                                bf16* __restrict__ o2) {
  const float* w = blockIdx.z == 0 ? w0 : (blockIdx.z == 1 ? w1 : w2);
  bf16* o = blockIdx.z == 0 ? o0 : (blockIdx.z == 1 ? o1 : o2);
  __shared__ float t[64][65];
  int h = blockIdx.y, d0 = blockIdx.x * 64;
  const float* src = w + ((size_t)h * DM + d0) * DKV;
  for (int i = threadIdx.x; i < 64 * 64; i += 256) {
    int r = i >> 6, c = i & 63;
    t[r][c] = src[(size_t)r * DKV + c];
  }
  __syncthreads();
  for (int i = threadIdx.x; i < 64 * 64; i += 256) {
    int kk = i >> 6, d = i & 63;
    o[((size_t)(h * 64 + kk)) * DM + d0 + d] = (bf16)t[d][kk];
  }
}

// ---------------- fused QKV projection GEMMs (128^2 tile, proven ~900 TF) -----------
// z=0: QH = Xq*Wqt, scale (1/32)*log2e; z=1: KH = Xk*Wkt; z=2: VT (transposed out)
__global__ __launch_bounds__(256) void gemm_qkv(const bf16* __restrict__ Xq, const bf16* __restrict__ Xk,
                                                const bf16* __restrict__ Xv, const bf16* __restrict__ Wqt,
                                                const bf16* __restrict__ Wkt, const bf16* __restrict__ Wvt,
                                                bf16* __restrict__ QH, bf16* __restrict__ KH,
                                                bf16* __restrict__ VT) {
  __shared__ bf16 sA[128 * 64];
  __shared__ bf16 sB[128 * 64];
  const int mode = blockIdx.z;
  const bf16* A  = mode == 0 ? Xq : (mode == 1 ? Xk : Xv);
  const bf16* Bt = mode == 0 ? Wqt : (mode == 1 ? Wkt : Wvt);
  const int tid = threadIdx.x;
  const int w = tid >> 6, l = tid & 63;
  const int c = l & 15, g4 = l >> 4;
  const int wm = w >> 1, wn = w & 1;
  const int m0 = blockIdx.y * 128, n0 = blockIdx.x * 128;

  f32x4 acc[4][4] = {};
  for (int kt = 0; kt < 1024; kt += 64) {
#pragma unroll
    for (int i = 0; i < 4; ++i) {
      int blk = i * 4 + w;
      int row = blk * 8 + (l >> 3);
      int g = (l & 7) ^ (row & 7);
      gload_lds16(A + ((size_t)(m0 + row)) * 1024 + kt + g * 8, (char*)sA + blk * 1024);
      gload_lds16(Bt + ((size_t)(n0 + row)) * 1024 + kt + g * 8, (char*)sB + blk * 1024);
    }
    __syncthreads();
#pragma unroll
    for (int ks = 0; ks < 2; ++ks) {
      bf16x8 af[4], bfr[4];
#pragma unroll
      for (int x = 0; x < 4; ++x) {
        int ar = wm * 64 + x * 16 + c;
        af[x] = *(const bf16x8*)((const char*)sA + ar * 128 + (((ks * 4 + g4) ^ (ar & 7)) * 16));
        int br = wn * 64 + x * 16 + c;
        bfr[x] = *(const bf16x8*)((const char*)sB + br * 128 + (((ks * 4 + g4) ^ (br & 7)) * 16));
      }
#pragma unroll
      for (int x = 0; x < 4; ++x)
#pragma unroll
        for (int y = 0; y < 4; ++y)
          acc[x][y] = __builtin_amdgcn_mfma_f32_16x16x32_bf16(af[x], bfr[y], acc[x][y], 0, 0, 0);
    }
    __syncthreads();
  }

  const int mm = m0 + wm * 64, nn = n0 + wn * 64;
  if (mode < 2) {
    bf16* O = mode == 0 ? QH : KH;
    const float s = (mode == 0) ? 0.03125f * 1.44269504088896f : 1.0f;
#pragma unroll
    for (int x = 0; x < 4; ++x)
#pragma unroll
      for (int y = 0; y < 4; ++y)
#pragma unroll
        for (int r = 0; r < 4; ++r) {
          int m = mm + x * 16 + g4 * 4 + r;
          int n = nn + y * 16 + c;
          O[(size_t)m * 1024 + n] = (bf16)(acc[x][y][r] * s);
        }
  } else {
    bf16* O = VT;  // Vt[(h*4+b)*64+dv][s]
#pragma unroll
    for (int x = 0; x < 4; ++x)
#pragma unroll
      for (int y = 0; y < 4; ++y) {
        int mb = mm + x * 16 + g4 * 4;
        int n = nn + y * 16 + c;
        int bb2 = mb >> 11, sidx = mb & 2047;
        int hh2 = n >> 6, dv = n & 63;
        unsigned int u0 = bfbits(acc[x][y][0]) | ((unsigned int)bfbits(acc[x][y][1]) << 16);
        unsigned int u1 = bfbits(acc[x][y][2]) | ((unsigned int)bfbits(acc[x][y][3]) << 16);
        *(uint2*)(O + ((size_t)((hh2 * 4 + bb2) * 64 + dv)) * LL + sidx) = make_uint2(u0, u1);
      }
  }
}

// ---------------- final projection GEMM (128^2, proven) ----------------
__global__ __launch_bounds__(256) void gemm_proj(const bf16* __restrict__ A, const bf16* __restrict__ Bt,
                                                 float* __restrict__ Out, const float* __restrict__ bias) {
  __shared__ bf16 sA[128 * 64];
  __shared__ bf16 sB[128 * 64];
  const int tid = threadIdx.x;
  const int w = tid >> 6, l = tid & 63;
  const int c = l & 15, g4 = l >> 4;
  const int wm = w >> 1, wn = w & 1;
  const int m0 = blockIdx.y * 128, n0 = blockIdx.x * 128;

  f32x4 acc[4][4] = {};
  for (int kt = 0; kt < 1024; kt += 64) {
#pragma unroll
    for (int i = 0; i < 4; ++i) {
      int blk = i * 4 + w;
      int row = blk * 8 + (l >> 3);
      int g = (l & 7) ^ (row & 7);
      gload_lds16(A + ((size_t)(m0 + row)) * 1024 + kt + g * 8, (char*)sA + blk * 1024);
      gload_lds16(Bt + ((size_t)(n0 + row)) * 1024 + kt + g * 8, (char*)sB + blk * 1024);
    }
    __syncthreads();
#pragma unroll
    for (int ks = 0; ks < 2; ++ks) {
      bf16x8 af[4], bfr[4];
#pragma unroll
      for (int x = 0; x < 4; ++x) {
        int ar = wm * 64 + x * 16 + c;
        af[x] = *(const bf16x8*)((const char*)sA + ar * 128 + (((ks * 4 + g4) ^ (ar & 7)) * 16));
        int br = wn * 64 + x * 16 + c;
        bfr[x] = *(const bf16x8*)((const char*)sB + br * 128 + (((ks * 4 + g4) ^ (br & 7)) * 16));
      }
#pragma unroll
      for (int x = 0; x < 4; ++x)
#pragma unroll
        for (int y = 0; y < 4; ++y)
          acc[x][y] = __builtin_amdgcn_mfma_f32_16x16x32_bf16(af[x], bfr[y], acc[x][y], 0, 0, 0);
    }
    __syncthreads();
  }

  const int mm = m0 + wm * 64, nn = n0 + wn * 64;
#pragma unroll
  for (int x = 0; x < 4; ++x)
#pragma unroll
    for (int y = 0; y < 4; ++y)
#pragma unroll
      for (int r = 0; r < 4; ++r) {
        int m = mm + x * 16 + g4 * 4 + r;
        int n = nn + y * 16 + c;
        Out[(size_t)m * 1024 + n] = acc[x][y][r] + bias[n];
      }
}

// ---------------- flash attention: 8 waves/block, 32 q/wave, 4 waves/SIMD ----------
// grid (64 bh FAST, 8 qtiles of 256) = 512 blocks x 8 waves -> 16 waves/CU (2 blk/CU,
// LDS 64KB). No-max exp2 softmax + ones-MFMA denominator (round-8, proven).
// __launch_bounds__(512,4) caps VGPR at 128 so 4 waves/SIMD actually materialize.
__global__ __launch_bounds__(512, 4) void attn_kernel(const bf16* __restrict__ qh,
                                                      const bf16* __restrict__ kh,
                                                      const bf16* __restrict__ vt,
                                                      bf16* __restrict__ o) {
  __shared__ bf16 sK[4][64 * 64];   // 32 KB, [kv][d] swizzled, 4-ring
  __shared__ bf16 sV[4][64 * 64];   // 32 KB, [dv][kv] swizzled, 4-ring
  const int tid = threadIdx.x, w = tid >> 6, l = tid & 63;
  const int c = l & 31, hi = l >> 5;
  const int bh = blockIdx.x, b = bh & 3, h = bh >> 2;   // bh fastest -> XCD = bh%8
  const int q0 = blockIdx.y * 256 + w * 32;             // wave owns rows q0..q0+31

  const bf16* qbase = qh + ((size_t)(b * LL)) * DM + h * 64;
  const bf16* kbase = kh + ((size_t)(b * LL)) * DM + h * 64;
  const bf16* vbase = vt + ((size_t)((h * 4 + b) * 64)) * LL;

  // Q fragments (B-operand): lane holds Q[q=q0+c][d=ks*16+hi*8 .. +8]
  bf16x8 qf[4];
#pragma unroll
  for (int ks = 0; ks < 4; ++ks)
    qf[ks] = *(const bf16x8*)(qbase + (size_t)(q0 + c) * DM + ks * 16 + hi * 8);

  bf16x8 onesf;
#pragma unroll
  for (int i = 0; i < 8; ++i) onesf[i] = (bf16)1.0f;

  f32x16 o0 = {}, o1 = {};    // O^T tiles [dv 0..31], [dv 32..63]; col q = q0+c
  f32x16 la = {};             // denominator accumulator (every reg = l[q])

  // 512 threads stage a 64x64 K tile + V tile: 1 granule each (2 gloads/thread)
  auto STAGE = [&](int bufi, int kv0) {
    int row = tid >> 3;                 // 0..63
    int g = (tid & 7) ^ (row & 7);      // inverse-swizzled source granule
    gload_lds16(kbase + (size_t)(kv0 + row) * DM + g * 8,
                (char*)sK[bufi] + w * 1024);
    gload_lds16(vbase + (size_t)row * LL + kv0 + g * 8,
                (char*)sV[bufi] + w * 1024);
  };

  // P = exp2(st) elementwise, pack to bf16 A-frag layout via plswap
  auto EXPPACK = [&](f32x16& st0, f32x16& st1, bf16x8* pb) {
#pragma unroll
    for (int r = 0; r < 16; ++r) st0[r] = fast_exp2(st0[r]);
#pragma unroll
    for (int r = 0; r < 16; ++r) st1[r] = fast_exp2(st1[r]);
#pragma unroll
    for (int t = 0; t < 2; ++t) {
      const f32x16& st = t ? st1 : st0;
      unsigned int u[4][2];
#pragma unroll
      for (int g2 = 0; g2 < 4; ++g2) {
        u[g2][0] = (unsigned int)bfbits(st[4 * g2 + 0]) | ((unsigned int)bfbits(st[4 * g2 + 1]) << 16);
        u[g2][1] = (unsigned int)bfbits(st[4 * g2 + 2]) | ((unsigned int)bfbits(st[4 * g2 + 3]) << 16);
      }
      u32x2 s0 = plswap(u[0][0], u[1][0], hi);
      u32x2 s1 = plswap(u[0][1], u[1][1], hi);
      u32x4 w0; w0.x = s0.x; w0.y = s1.x; w0.z = s0.y; w0.w = s1.y;
      pb[2 * t] = __builtin_bit_cast(bf16x8, w0);
      u32x2 s2 = plswap(u[2][0], u[3][0], hi);
      u32x2 s3 = plswap(u[2][1], u[3][1], hi);
      u32x4 w1; w1.x = s2.x; w1.y = s3.x; w1.z = s2.y; w1.w = s3.y;
      pb[2 * t + 1] = __builtin_bit_cast(bf16x8, w1);
    }
  };

  auto TILE = [&](int bufi) {
    const char* Kb = (const char*)sK[bufi];
    const char* Vb = (const char*)sV[bufi];

    // QK: K fragment pairs loaded just-in-time (keeps live kf at 8 regs)
    f32x16 st0 = {}, st1 = {};
    __builtin_amdgcn_s_setprio(1);
#pragma unroll
    for (int ks = 0; ks < 4; ++ks) {
      int slot = ((ks * 2 + hi) ^ (c & 7)) * 16;
      bf16x8 k0 = *(const bf16x8*)(Kb + c * 128 + slot);
      bf16x8 k1 = *(const bf16x8*)(Kb + (32 + c) * 128 + slot);
      st0 = __builtin_amdgcn_mfma_f32_32x32x16_bf16(k0, qf[ks], st0, 0, 0, 0);
      st1 = __builtin_amdgcn_mfma_f32_32x32x16_bf16(k1, qf[ks], st1, 0, 0, 0);
    }
    __builtin_amdgcn_s_setprio(0);

    bf16x8 pb[4];
    EXPPACK(st0, st1, pb);

    __builtin_amdgcn_s_setprio(1);
#pragma unroll
    for (int ks = 0; ks < 4; ++ks) {
      int slot = ((ks * 2 + hi) ^ (c & 7)) * 16;
      bf16x8 v0 = *(const bf16x8*)(Vb + c * 128 + slot);
      bf16x8 v1 = *(const bf16x8*)(Vb + (32 + c) * 128 + slot);
      o0 = __builtin_amdgcn_mfma_f32_32x32x16_bf16(v0, pb[ks], o0, 0, 0, 0);
      o1 = __builtin_amdgcn_mfma_f32_32x32x16_bf16(v1, pb[ks], o1, 0, 0, 0);
      la = __builtin_amdgcn_mfma_f32_32x32x16_bf16(onesf, pb[ks], la, 0, 0, 0);
    }
    __builtin_amdgcn_s_setprio(0);
  };

  // prologue: stage tiles 0,1 (4 loads/thread outstanding)
  STAGE(0, 0);
  STAGE(1, 64);

  // 16 windows; each: barrier, stage 2 tiles, counted wait, compute 2 tiles
  for (int wd = 0; wd < 16; ++wd) {
    __builtin_amdgcn_s_barrier();      // prev window's compute done -> safe to overwrite
    int t2 = 2 * wd + 2;
    if (t2 < NT) {
      STAGE(t2 & 3, t2 * 64);
      STAGE((t2 + 1) & 3, (t2 + 1) * 64);
      asm volatile("s_waitcnt vmcnt(4)" ::: "memory");   // tiles 2wd,2wd+1 resident
    } else {
      asm volatile("s_waitcnt vmcnt(0)" ::: "memory");
    }
    TILE((2 * wd) & 3);
    TILE((2 * wd + 1) & 3);
  }

  // ---- epilogue: O[q][dv] = oacc / l ----
  bf16* ob = o + ((size_t)(b * LL)) * DM + h * 64;
  float inv = 1.0f / la[0];
#pragma unroll
  for (int dt = 0; dt < 2; ++dt) {
    const f32x16& oc = dt ? o1 : o0;
#pragma unroll
    for (int rg = 0; rg < 4; ++rg) {
      int dv0 = dt * 32 + rg * 8 + hi * 4;
      unsigned int u0 = (unsigned int)bfbits(oc[rg * 4 + 0] * inv) |
                        ((unsigned int)bfbits(oc[rg * 4 + 1] * inv) << 16);
      unsigned int u1 = (unsigned int)bfbits(oc[rg * 4 + 2] * inv) |
                        ((unsigned int)bfbits(oc[rg * 4 + 3] * inv) << 16);
      *(uint2*)(ob + (size_t)(q0 + c) * DM + dv0) = make_uint2(u0, u1);
    }
  }
}

extern "C" void kernel_launch(void* const* d_in, const int* in_sizes, int n_in,
                              void* d_out, int out_size, void* d_ws, size_t ws_size,
                              hipStream_t stream) {
  const float* q  = (const float*)d_in[0];
  const float* k  = (const float*)d_in[1];
  const float* v  = (const float*)d_in[2];
  const float* wq = (const float*)d_in[3];
  const float* wk = (const float*)d_in[4];
  const float* wv = (const float*)d_in[5];
  const float* pw = (const float*)d_in[6];
  const float* pb = (const float*)d_in[7];
  float* out = (float*)d_out;

  char* ws = (char*)d_ws;
  const size_t SX = (size_t)MT * DM * 2;   // 16.8 MB
  const size_t SW = (size_t)DM * DM * 2;   // 2 MB
  bf16* Xq  = (bf16*)(ws);
  bf16* Xk  = (bf16*)(ws + SX);
  bf16* Xv  = (bf16*)(ws + 2 * SX);
  bf16* Wqt = (bf16*)(ws + 3 * SX);
  bf16* Wkt = (bf16*)(ws + 3 * SX + SW);
  bf16* Wvt = (bf16*)(ws + 3 * SX + 2 * SW);
  bf16* Wp  = (bf16*)(ws + 3 * SX + 3 * SW);
  bf16* QH  = (bf16*)(ws + 3 * SX + 4 * SW);
  bf16* KH  = (bf16*)(ws + 4 * SX + 4 * SW);
  bf16* VT  = (bf16*)(ws + 5 * SX + 4 * SW);
  bf16* OO  = Xq;  // reuse: Xq dead after gemm_qkv

  const int nx8 = MT * DM / 8;
  cast3_f32_to_bf16<<<dim3(nx8 / 256, 3), 256, 0, stream>>>(q, k, v, Xq, Xk, Xv, nx8);
  const int nw8 = DM * DM / 8;
  cast_f32_to_bf16<<<dim3(nw8 / 256), 256, 0, stream>>>(pw, Wp, nw8);
  repack_w<<<dim3(16, 16, 3), 256, 0, stream>>>(wq, wk, wv, Wqt, Wkt, Wvt);

  gemm_qkv<<<dim3(8, 64, 3), 256, 0, stream>>>(Xq, Xk, Xv, Wqt, Wkt, Wvt, QH, KH, VT);

  attn_kernel<<<dim3(64, 8), 512, 0, stream>>>(QH, KH, VT, OO);

  gemm_proj<<<dim3(8, 64), 256, 0, stream>>>(OO, Wp, out, pb);
}

// Round 11
// 223.336 us; speedup vs baseline: 1.0562x; 1.0323x over previous
//
#include <hip/hip_runtime.h>
#include <hip/hip_bf16.h>
#include <stdint.h>

#define NH 16
#define DM 1024
#define DKV 64
#define BB 4
#define LL 2048
#define MT (BB*LL)   // 8192 rows total
#define NT (LL/64)   // 32 kv tiles

typedef __bf16 bf16;
typedef __bf16 bf16x8 __attribute__((ext_vector_type(8)));
typedef float f32x4 __attribute__((ext_vector_type(4)));
typedef float f32x16 __attribute__((ext_vector_type(16)));
typedef unsigned int u32x2 __attribute__((ext_vector_type(2)));
typedef unsigned int u32x4 __attribute__((ext_vector_type(4)));

__device__ __forceinline__ void gload_lds16(const void* g, void* l) {
  __builtin_amdgcn_global_load_lds(
      (const __attribute__((address_space(1))) unsigned int*)g,
      (__attribute__((address_space(3))) unsigned int*)l, 16, 0, 0);
}

__device__ __forceinline__ unsigned short bfbits(float x) {
  bf16 b = (bf16)x;
  return __builtin_bit_cast(unsigned short, b);
}

// single-instruction 2^x (v_exp_f32); exp2f() routes through ocml (round-3 regression)
__device__ __forceinline__ float fast_exp2(float x) {
#if defined(__has_builtin)
#if __has_builtin(__builtin_amdgcn_exp2f)
  return __builtin_amdgcn_exp2f(x);
#else
  float r; asm("v_exp_f32 %0, %1" : "=v"(r) : "v"(x)); return r;
#endif
#else
  float r; asm("v_exp_f32 %0, %1" : "=v"(r) : "v"(x)); return r;
#endif
}

#if defined(__has_builtin)
#if __has_builtin(__builtin_amdgcn_permlane32_swap)
#define HAVE_PLSWAP 1
#endif
#endif

// swap: r.x = (lane<32)? a : b[partner];  r.y = (lane<32)? a[partner] : b
__device__ __forceinline__ u32x2 plswap(unsigned int a, unsigned int b, int hi) {
#ifdef HAVE_PLSWAP
  auto rr = __builtin_amdgcn_permlane32_swap(a, b, false, false);
  u32x2 r; r.x = rr[0]; r.y = rr[1];
  return r;
#else
  unsigned int pa = (unsigned int)__shfl_xor((int)a, 32);
  unsigned int pb_ = (unsigned int)__shfl_xor((int)b, 32);
  u32x2 r;
  r.x = hi ? pb_ : a;
  r.y = hi ? b : pa;
  return r;
#endif
}

// ---------------- cast f32 -> bf16, 8 elems/thread; grid.y selects buffer ------------
__global__ __launch_bounds__(256) void cast3_f32_to_bf16(const float* __restrict__ i0,
                                                         const float* __restrict__ i1,
                                                         const float* __restrict__ i2,
                                                         bf16* __restrict__ o0,
                                                         bf16* __restrict__ o1,
                                                         bf16* __restrict__ o2, int n8) {
  const float* in = blockIdx.y == 0 ? i0 : (blockIdx.y == 1 ? i1 : i2);
  bf16* out = blockIdx.y == 0 ? o0 : (blockIdx.y == 1 ? o1 : o2);
  int i = blockIdx.x * blockDim.x + threadIdx.x;
  if (i >= n8) return;
  const float4* p = (const float4*)in + (size_t)i * 2;
  float4 a = p[0], b = p[1];
  bf16x8 r;
  r[0] = (bf16)a.x; r[1] = (bf16)a.y; r[2] = (bf16)a.z; r[3] = (bf16)a.w;
  r[4] = (bf16)b.x; r[5] = (bf16)b.y; r[6] = (bf16)b.z; r[7] = (bf16)b.w;
  *((bf16x8*)out + i) = r;
}

__global__ __launch_bounds__(256) void cast_f32_to_bf16(const float* __restrict__ in,
                                                        bf16* __restrict__ out, int n8) {
  int i = blockIdx.x * blockDim.x + threadIdx.x;
  if (i >= n8) return;
  const float4* p = (const float4*)in + (size_t)i * 2;
  float4 a = p[0], b = p[1];
  bf16x8 r;
  r[0] = (bf16)a.x; r[1] = (bf16)a.y; r[2] = (bf16)a.z; r[3] = (bf16)a.w;
  r[4] = (bf16)b.x; r[5] = (bf16)b.y; r[6] = (bf16)b.z; r[7] = (bf16)b.w;
  *((bf16x8*)out + i) = r;
}

// ---------------- repack w[h][d][kk] (f32) -> wt[h*64+kk][d] (bf16) ----------------
__global__ __launch_bounds__(256) void repack_w(const float* __restrict__ w0, const float* __restrict__ w1,
                                                const float* __restrict__ w2,
                                                bf16* __restrict__ o0, bf16* __restrict__ o1,
                                                bf16* __restrict__ o2) {
  const float* w = blockIdx.z == 0 ? w0 : (blockIdx.z == 1 ? w1 : w2);
  bf16* o = blockIdx.z == 0 ? o0 : (blockIdx.z == 1 ? o1 : o2);
  __shared__ float t[64][65];
  int h = blockIdx.y, d0 = blockIdx.x * 64;
  const float* src = w + ((size_t)h * DM + d0) * DKV;
  for (int i = threadIdx.x; i < 64 * 64; i += 256) {
    int r = i >> 6, c = i & 63;
    t[r][c] = src[(size_t)r * DKV + c];
  }
  __syncthreads();
  for (int i = threadIdx.x; i < 64 * 64; i += 256) {
    int kk = i >> 6, d = i & 63;
    o[((size_t)(h * 64 + kk)) * DM + d0 + d] = (bf16)t[d][kk];
  }
}

// ---------------- fused QKV projection GEMMs (128^2 tile, proven ~900 TF) -----------
// z=0: QH = Xq*Wqt, scale (1/32)*log2e; z=1: KH = Xk*Wkt; z=2: VT (transposed out)
__global__ __launch_bounds__(256) void gemm_qkv(const bf16* __restrict__ Xq, const bf16* __restrict__ Xk,
                                                const bf16* __restrict__ Xv, const bf16* __restrict__ Wqt,
                                                const bf16* __restrict__ Wkt, const bf16* __restrict__ Wvt,
                                                bf16* __restrict__ QH, bf16* __restrict__ KH,
                                                bf16* __restrict__ VT) {
  __shared__ bf16 sA[128 * 64];
  __shared__ bf16 sB[128 * 64];
  const int mode = blockIdx.z;
  const bf16* A  = mode == 0 ? Xq : (mode == 1 ? Xk : Xv);
  const bf16* Bt = mode == 0 ? Wqt : (mode == 1 ? Wkt : Wvt);
  const int tid = threadIdx.x;
  const int w = tid >> 6, l = tid & 63;
  const int c = l & 15, g4 = l >> 4;
  const int wm = w >> 1, wn = w & 1;
  const int m0 = blockIdx.y * 128, n0 = blockIdx.x * 128;

  f32x4 acc[4][4] = {};
  for (int kt = 0; kt < 1024; kt += 64) {
#pragma unroll
    for (int i = 0; i < 4; ++i) {
      int blk = i * 4 + w;
      int row = blk * 8 + (l >> 3);
      int g = (l & 7) ^ (row & 7);
      gload_lds16(A + ((size_t)(m0 + row)) * 1024 + kt + g * 8, (char*)sA + blk * 1024);
      gload_lds16(Bt + ((size_t)(n0 + row)) * 1024 + kt + g * 8, (char*)sB + blk * 1024);
    }
    __syncthreads();
#pragma unroll
    for (int ks = 0; ks < 2; ++ks) {
      bf16x8 af[4], bfr[4];
#pragma unroll
      for (int x = 0; x < 4; ++x) {
        int ar = wm * 64 + x * 16 + c;
        af[x] = *(const bf16x8*)((const char*)sA + ar * 128 + (((ks * 4 + g4) ^ (ar & 7)) * 16));
        int br = wn * 64 + x * 16 + c;
        bfr[x] = *(const bf16x8*)((const char*)sB + br * 128 + (((ks * 4 + g4) ^ (br & 7)) * 16));
      }
#pragma unroll
      for (int x = 0; x < 4; ++x)
#pragma unroll
        for (int y = 0; y < 4; ++y)
          acc[x][y] = __builtin_amdgcn_mfma_f32_16x16x32_bf16(af[x], bfr[y], acc[x][y], 0, 0, 0);
    }
    __syncthreads();
  }

  const int mm = m0 + wm * 64, nn = n0 + wn * 64;
  if (mode < 2) {
    bf16* O = mode == 0 ? QH : KH;
    const float s = (mode == 0) ? 0.03125f * 1.44269504088896f : 1.0f;
#pragma unroll
    for (int x = 0; x < 4; ++x)
#pragma unroll
      for (int y = 0; y < 4; ++y)
#pragma unroll
        for (int r = 0; r < 4; ++r) {
          int m = mm + x * 16 + g4 * 4 + r;
          int n = nn + y * 16 + c;
          O[(size_t)m * 1024 + n] = (bf16)(acc[x][y][r] * s);
        }
  } else {
    bf16* O = VT;  // Vt[(h*4+b)*64+dv][s]
#pragma unroll
    for (int x = 0; x < 4; ++x)
#pragma unroll
      for (int y = 0; y < 4; ++y) {
        int mb = mm + x * 16 + g4 * 4;
        int n = nn + y * 16 + c;
        int bb2 = mb >> 11, sidx = mb & 2047;
        int hh2 = n >> 6, dv = n & 63;
        unsigned int u0 = bfbits(acc[x][y][0]) | ((unsigned int)bfbits(acc[x][y][1]) << 16);
        unsigned int u1 = bfbits(acc[x][y][2]) | ((unsigned int)bfbits(acc[x][y][3]) << 16);
        *(uint2*)(O + ((size_t)((hh2 * 4 + bb2) * 64 + dv)) * LL + sidx) = make_uint2(u0, u1);
      }
  }
}

// ---------------- final projection GEMM (128^2, proven) ----------------
__global__ __launch_bounds__(256) void gemm_proj(const bf16* __restrict__ A, const bf16* __restrict__ Bt,
                                                 float* __restrict__ Out, const float* __restrict__ bias) {
  __shared__ bf16 sA[128 * 64];
  __shared__ bf16 sB[128 * 64];
  const int tid = threadIdx.x;
  const int w = tid >> 6, l = tid & 63;
  const int c = l & 15, g4 = l >> 4;
  const int wm = w >> 1, wn = w & 1;
  const int m0 = blockIdx.y * 128, n0 = blockIdx.x * 128;

  f32x4 acc[4][4] = {};
  for (int kt = 0; kt < 1024; kt += 64) {
#pragma unroll
    for (int i = 0; i < 4; ++i) {
      int blk = i * 4 + w;
      int row = blk * 8 + (l >> 3);
      int g = (l & 7) ^ (row & 7);
      gload_lds16(A + ((size_t)(m0 + row)) * 1024 + kt + g * 8, (char*)sA + blk * 1024);
      gload_lds16(Bt + ((size_t)(n0 + row)) * 1024 + kt + g * 8, (char*)sB + blk * 1024);
    }
    __syncthreads();
#pragma unroll
    for (int ks = 0; ks < 2; ++ks) {
      bf16x8 af[4], bfr[4];
#pragma unroll
      for (int x = 0; x < 4; ++x) {
        int ar = wm * 64 + x * 16 + c;
        af[x] = *(const bf16x8*)((const char*)sA + ar * 128 + (((ks * 4 + g4) ^ (ar & 7)) * 16));
        int br = wn * 64 + x * 16 + c;
        bfr[x] = *(const bf16x8*)((const char*)sB + br * 128 + (((ks * 4 + g4) ^ (br & 7)) * 16));
      }
#pragma unroll
      for (int x = 0; x < 4; ++x)
#pragma unroll
        for (int y = 0; y < 4; ++y)
          acc[x][y] = __builtin_amdgcn_mfma_f32_16x16x32_bf16(af[x], bfr[y], acc[x][y], 0, 0, 0);
    }
    __syncthreads();
  }

  const int mm = m0 + wm * 64, nn = n0 + wn * 64;
#pragma unroll
  for (int x = 0; x < 4; ++x)
#pragma unroll
    for (int y = 0; y < 4; ++y)
#pragma unroll
      for (int r = 0; r < 4; ++r) {
        int m = mm + x * 16 + g4 * 4 + r;
        int n = nn + y * 16 + c;
        Out[(size_t)m * 1024 + n] = acc[x][y][r] + bias[n];
      }
}

// ---------------- flash attention: 8 waves/block, 32 q/wave, NO VGPR cap -----------
// grid (64 bh FAST, 8 qtiles of 256) = 512 blocks x 8 waves -> 2 blk/CU (LDS 64KB)
// = 16 waves/CU = 4 waves/SIMD when VGPR <= 128. Round-10 used (512,4) which forced
// the allocator to 64 VGPR and spilled the accumulators (first dispatch 190us scratch
// warmup, MfmaUtil down). (512,2) keeps the ~115-reg state in registers.
__global__ __launch_bounds__(512, 2) void attn_kernel(const bf16* __restrict__ qh,
                                                      const bf16* __restrict__ kh,
                                                      const bf16* __restrict__ vt,
                                                      bf16* __restrict__ o) {
  __shared__ bf16 sK[4][64 * 64];   // 32 KB, [kv][d] swizzled, 4-ring
  __shared__ bf16 sV[4][64 * 64];   // 32 KB, [dv][kv] swizzled, 4-ring
  const int tid = threadIdx.x, w = tid >> 6, l = tid & 63;
  const int c = l & 31, hi = l >> 5;
  const int bh = blockIdx.x, b = bh & 3, h = bh >> 2;   // bh fastest -> XCD = bh%8
  const int q0 = blockIdx.y * 256 + w * 32;             // wave owns rows q0..q0+31

  const bf16* qbase = qh + ((size_t)(b * LL)) * DM + h * 64;
  const bf16* kbase = kh + ((size_t)(b * LL)) * DM + h * 64;
  const bf16* vbase = vt + ((size_t)((h * 4 + b) * 64)) * LL;

  // Q fragments (B-operand): lane holds Q[q=q0+c][d=ks*16+hi*8 .. +8]
  bf16x8 qf[4];
#pragma unroll
  for (int ks = 0; ks < 4; ++ks)
    qf[ks] = *(const bf16x8*)(qbase + (size_t)(q0 + c) * DM + ks * 16 + hi * 8);

  bf16x8 onesf;
#pragma unroll
  for (int i = 0; i < 8; ++i) onesf[i] = (bf16)1.0f;

  f32x16 o0 = {}, o1 = {};    // O^T tiles [dv 0..31], [dv 32..63]; col q = q0+c
  f32x16 la = {};             // denominator accumulator (every reg = l[q])

  // 512 threads stage a 64x64 K tile + V tile: 1 granule each (2 gloads/thread)
  auto STAGE = [&](int bufi, int kv0) {
    int row = tid >> 3;                 // 0..63
    int g = (tid & 7) ^ (row & 7);      // inverse-swizzled source granule
    gload_lds16(kbase + (size_t)(kv0 + row) * DM + g * 8,
                (char*)sK[bufi] + w * 1024);
    gload_lds16(vbase + (size_t)row * LL + kv0 + g * 8,
                (char*)sV[bufi] + w * 1024);
  };

  // P = exp2(st) elementwise, pack to bf16 A-frag layout via plswap
  auto EXPPACK = [&](f32x16& st0, f32x16& st1, bf16x8* pb) {
#pragma unroll
    for (int r = 0; r < 16; ++r) st0[r] = fast_exp2(st0[r]);
#pragma unroll
    for (int r = 0; r < 16; ++r) st1[r] = fast_exp2(st1[r]);
#pragma unroll
    for (int t = 0; t < 2; ++t) {
      const f32x16& st = t ? st1 : st0;
      unsigned int u[4][2];
#pragma unroll
      for (int g2 = 0; g2 < 4; ++g2) {
        u[g2][0] = (unsigned int)bfbits(st[4 * g2 + 0]) | ((unsigned int)bfbits(st[4 * g2 + 1]) << 16);
        u[g2][1] = (unsigned int)bfbits(st[4 * g2 + 2]) | ((unsigned int)bfbits(st[4 * g2 + 3]) << 16);
      }
      u32x2 s0 = plswap(u[0][0], u[1][0], hi);
      u32x2 s1 = plswap(u[0][1], u[1][1], hi);
      u32x4 w0; w0.x = s0.x; w0.y = s1.x; w0.z = s0.y; w0.w = s1.y;
      pb[2 * t] = __builtin_bit_cast(bf16x8, w0);
      u32x2 s2 = plswap(u[2][0], u[3][0], hi);
      u32x2 s3 = plswap(u[2][1], u[3][1], hi);
      u32x4 w1; w1.x = s2.x; w1.y = s3.x; w1.z = s2.y; w1.w = s3.y;
      pb[2 * t + 1] = __builtin_bit_cast(bf16x8, w1);
    }
  };

  auto TILE = [&](int bufi) {
    const char* Kb = (const char*)sK[bufi];
    const char* Vb = (const char*)sV[bufi];

    // QK: K fragment pairs loaded just-in-time (keeps live kf at 8 regs)
    f32x16 st0 = {}, st1 = {};
    __builtin_amdgcn_s_setprio(1);
#pragma unroll
    for (int ks = 0; ks < 4; ++ks) {
      int slot = ((ks * 2 + hi) ^ (c & 7)) * 16;
      bf16x8 k0 = *(const bf16x8*)(Kb + c * 128 + slot);
      bf16x8 k1 = *(const bf16x8*)(Kb + (32 + c) * 128 + slot);
      st0 = __builtin_amdgcn_mfma_f32_32x32x16_bf16(k0, qf[ks], st0, 0, 0, 0);
      st1 = __builtin_amdgcn_mfma_f32_32x32x16_bf16(k1, qf[ks], st1, 0, 0, 0);
    }
    __builtin_amdgcn_s_setprio(0);

    bf16x8 pb[4];
    EXPPACK(st0, st1, pb);

    __builtin_amdgcn_s_setprio(1);
#pragma unroll
    for (int ks = 0; ks < 4; ++ks) {
      int slot = ((ks * 2 + hi) ^ (c & 7)) * 16;
      bf16x8 v0 = *(const bf16x8*)(Vb + c * 128 + slot);
      bf16x8 v1 = *(const bf16x8*)(Vb + (32 + c) * 128 + slot);
      o0 = __builtin_amdgcn_mfma_f32_32x32x16_bf16(v0, pb[ks], o0, 0, 0, 0);
      o1 = __builtin_amdgcn_mfma_f32_32x32x16_bf16(v1, pb[ks], o1, 0, 0, 0);
      la = __builtin_amdgcn_mfma_f32_32x32x16_bf16(onesf, pb[ks], la, 0, 0, 0);
    }
    __builtin_amdgcn_s_setprio(0);
  };

  // prologue: stage tiles 0,1 (4 loads/thread outstanding)
  STAGE(0, 0);
  STAGE(1, 64);

  // 16 windows; each: barrier, stage 2 tiles, counted wait, compute 2 tiles
  for (int wd = 0; wd < 16; ++wd) {
    __builtin_amdgcn_s_barrier();      // prev window's compute done -> safe to overwrite
    int t2 = 2 * wd + 2;
    if (t2 < NT) {
      STAGE(t2 & 3, t2 * 64);
      STAGE((t2 + 1) & 3, (t2 + 1) * 64);
      asm volatile("s_waitcnt vmcnt(4)" ::: "memory");   // tiles 2wd,2wd+1 resident
    } else {
      asm volatile("s_waitcnt vmcnt(0)" ::: "memory");
    }
    TILE((2 * wd) & 3);
    TILE((2 * wd + 1) & 3);
  }

  // ---- epilogue: O[q][dv] = oacc / l ----
  bf16* ob = o + ((size_t)(b * LL)) * DM + h * 64;
  float inv = 1.0f / la[0];
#pragma unroll
  for (int dt = 0; dt < 2; ++dt) {
    const f32x16& oc = dt ? o1 : o0;
#pragma unroll
    for (int rg = 0; rg < 4; ++rg) {
      int dv0 = dt * 32 + rg * 8 + hi * 4;
      unsigned int u0 = (unsigned int)bfbits(oc[rg * 4 + 0] * inv) |
                        ((unsigned int)bfbits(oc[rg * 4 + 1] * inv) << 16);
      unsigned int u1 = (unsigned int)bfbits(oc[rg * 4 + 2] * inv) |
                        ((unsigned int)bfbits(oc[rg * 4 + 3] * inv) << 16);
      *(uint2*)(ob + (size_t)(q0 + c) * DM + dv0) = make_uint2(u0, u1);
    }
  }
}

extern "C" void kernel_launch(void* const* d_in, const int* in_sizes, int n_in,
                              void* d_out, int out_size, void* d_ws, size_t ws_size,
                              hipStream_t stream) {
  const float* q  = (const float*)d_in[0];
  const float* k  = (const float*)d_in[1];
  const float* v  = (const float*)d_in[2];
  const float* wq = (const float*)d_in[3];
  const float* wk = (const float*)d_in[4];
  const float* wv = (const float*)d_in[5];
  const float* pw = (const float*)d_in[6];
  const float* pb = (const float*)d_in[7];
  float* out = (float*)d_out;

  char* ws = (char*)d_ws;
  const size_t SX = (size_t)MT * DM * 2;   // 16.8 MB
  const size_t SW = (size_t)DM * DM * 2;   // 2 MB
  bf16* Xq  = (bf16*)(ws);
  bf16* Xk  = (bf16*)(ws + SX);
  bf16* Xv  = (bf16*)(ws + 2 * SX);
  bf16* Wqt = (bf16*)(ws + 3 * SX);
  bf16* Wkt = (bf16*)(ws + 3 * SX + SW);
  bf16* Wvt = (bf16*)(ws + 3 * SX + 2 * SW);
  bf16* Wp  = (bf16*)(ws + 3 * SX + 3 * SW);
  bf16* QH  = (bf16*)(ws + 3 * SX + 4 * SW);
  bf16* KH  = (bf16*)(ws + 4 * SX + 4 * SW);
  bf16* VT  = (bf16*)(ws + 5 * SX + 4 * SW);
  bf16* OO  = Xq;  // reuse: Xq dead after gemm_qkv

  const int nx8 = MT * DM / 8;
  cast3_f32_to_bf16<<<dim3(nx8 / 256, 3), 256, 0, stream>>>(q, k, v, Xq, Xk, Xv, nx8);
  const int nw8 = DM * DM / 8;
  cast_f32_to_bf16<<<dim3(nw8 / 256), 256, 0, stream>>>(pw, Wp, nw8);
  repack_w<<<dim3(16, 16, 3), 256, 0, stream>>>(wq, wk, wv, Wqt, Wkt, Wvt);

  gemm_qkv<<<dim3(8, 64, 3), 256, 0, stream>>>(Xq, Xk, Xv, Wqt, Wkt, Wvt, QH, KH, VT);

  attn_kernel<<<dim3(64, 8), 512, 0, stream>>>(QH, KH, VT, OO);

  gemm_proj<<<dim3(8, 64), 256, 0, stream>>>(OO, Wp, out, pb);
}